// Round 4
// baseline (415.787 us; speedup 1.0000x reference)
//
#include <hip/hip_runtime.h>

#define B_   32
#define L_   512
#define D_   384
#define M_   (B_*L_)    // 16384 rows
#define KTOT (D_*3)     // 1152 GEMM K

typedef __bf16 bf16x8 __attribute__((ext_vector_type(8)));
typedef float  floatx4 __attribute__((ext_vector_type(4)));

// ---------------- conversion: x fp32 -> bf16 ----------------
__global__ __launch_bounds__(256) void cvt_kernel(const float* __restrict__ x,
                                                  __bf16* __restrict__ xb, int n4)
{
    int i = blockIdx.x * 256 + threadIdx.x;
    if (i >= n4) return;
    const float4 v = ((const float4*)x)[i];
    __bf16* o = xb + (size_t)i * 4;
    o[0] = (__bf16)v.x; o[1] = (__bf16)v.y; o[2] = (__bf16)v.z; o[3] = (__bf16)v.w;
}

// ---------------- weight repack (all 4 convs in one launch) ----------------
// w[o][i][k] fp32 -> Wt[o][k*384+i] bf16
__global__ __launch_bounds__(256) void repack4_kernel(const float* __restrict__ wa,
                                                      const float* __restrict__ wb,
                                                      const float* __restrict__ wc,
                                                      const float* __restrict__ wd,
                                                      __bf16* __restrict__ oa,
                                                      __bf16* __restrict__ ob,
                                                      __bf16* __restrict__ oc,
                                                      __bf16* __restrict__ od)
{
    int idx = blockIdx.x * 256 + threadIdx.x;
    if (idx >= D_ * KTOT) return;
    const float* w; __bf16* o_;
    switch (blockIdx.y) {
        case 0:  w = wa; o_ = oa; break;
        case 1:  w = wb; o_ = ob; break;
        case 2:  w = wc; o_ = oc; break;
        default: w = wd; o_ = od; break;
    }
    int o  = idx / KTOT;
    int kk = idx - o * KTOT;
    int k  = kk / D_;
    int i  = kk - k * D_;
    o_[idx] = (__bf16)w[(o * D_ + i) * 3 + k];
}

// ---------------- conv-as-GEMM, LDS-free fragment loads ----------------
// C = relu(shiftA @ Wt^T + bias); A:[M_,384] bf16 row-major, W:[384,1152] bf16.
// MFMA A-frag (16x16x32): lane holds A[m=lane&15][k=quad*8+j] -> one contiguous
// bf16x8 global load; same for the W row. No LDS, no barriers in the main loop:
// per-lane base pointers + uniform immediate offsets (max 2240B < 4096 signed).
// Block = 2 waves (BM=64 rows, BN=128 cols) -> grid 256x3=768 = exactly
// 3 blocks/CU, balanced. Waves share A addresses -> L1 reuse; W is 0.9MB
// total -> L2-resident.
#define BM 64
#define BN 128

__global__ __launch_bounds__(128, 2) void conv_gemm(const __bf16* __restrict__ A,
                                                    const __bf16* __restrict__ W,
                                                    const float* __restrict__ bias,
                                                    __bf16* __restrict__ C)
{
    __shared__ __bf16 Cs[2][64 * 72];     // epilogue transpose only

    const int m0 = blockIdx.x * BM;
    const int n0 = blockIdx.y * BN;
    const int l0 = m0 & 511;              // row within sequence (64 | 512: no crossing)
    const int b0 = m0 - l0;               // sequence base row

    const int tid  = threadIdx.x;
    const int wave = tid >> 6;
    const int lane = tid & 63;
    const int wn   = wave * 64;
    const int quad = lane >> 4;
    const int lx   = lane & 15;

    bf16x8 kz;
#pragma unroll
    for (int z = 0; z < 8; z++) kz[z] = (__bf16)0.f;

    floatx4 acc[4][4];
#pragma unroll
    for (int mi = 0; mi < 4; mi++)
#pragma unroll
        for (int ni = 0; ni < 4; ni++)
#pragma unroll
            for (int r = 0; r < 4; r++) acc[mi][ni][r] = 0.f;

    // per-lane base pointers; quad*16 folded in.
    // offset(it,s) = it*64 + s*768 bytes serves BOTH operands:
    //   A: +s*768 = +s rows (D_*2 bytes/row);  B: +s*768 = +s*384 k-elems.
    const char* pa[4];
    bool ok[4][3];
#pragma unroll
    for (int mi = 0; mi < 4; mi++) {
        int lrow = l0 + mi * 16 + lx - 1;               // local row for s=0
        pa[mi] = (const char*)A + (size_t)(b0 + lrow) * (D_ * 2) + quad * 16;
#pragma unroll
        for (int s = 0; s < 3; s++) ok[mi][s] = (unsigned)(lrow + s) < (unsigned)L_;
    }
    const char* pb[4];
#pragma unroll
    for (int ni = 0; ni < 4; ni++)
        pb[ni] = (const char*)W + (size_t)(n0 + wn + ni * 16 + lx) * (KTOT * 2) + quad * 16;

#pragma unroll
    for (int it = 0; it < 12; it++) {
#pragma unroll
        for (int s = 0; s < 3; s++) {
            const int off = it * 64 + s * 768;          // uniform -> inst offset imm
            bf16x8 af[4], bg[4];
#pragma unroll
            for (int mi = 0; mi < 4; mi++) {
                af[mi] = *(const bf16x8*)(pa[mi] + off);   // row l+s-1, col i0
                if (!ok[mi][s]) af[mi] = kz;
            }
#pragma unroll
            for (int ni = 0; ni < 4; ni++)
                bg[ni] = *(const bf16x8*)(pb[ni] + off);
#pragma unroll
            for (int mi = 0; mi < 4; mi++)
#pragma unroll
                for (int ni = 0; ni < 4; ni++)
                    acc[mi][ni] = __builtin_amdgcn_mfma_f32_16x16x32_bf16(af[mi], bg[ni], acc[mi][ni], 0, 0, 0);
        }
    }

    // epilogue: bias+relu -> LDS (row-major, pad 72) -> coalesced 16B stores
    __bf16* cw = Cs[wave];
#pragma unroll
    for (int mi = 0; mi < 4; mi++) {
#pragma unroll
        for (int ni = 0; ni < 4; ni++) {
            int col = ni * 16 + lx;
            float bv = bias[n0 + wn + col];
#pragma unroll
            for (int r = 0; r < 4; r++) {
                int row = mi * 16 + quad * 4 + r;
                float v = acc[mi][ni][r] + bv;
                v = v > 0.f ? v : 0.f;
                cw[row * 72 + col] = (__bf16)v;
            }
        }
    }
    __syncthreads();
#pragma unroll
    for (int c = 0; c < 8; c++) {
        int idx = c * 64 + lane;
        int row = idx >> 3, ch = idx & 7;
        bf16x8 v = *(const bf16x8*)(&cw[row * 72 + ch * 8]);
        *(bf16x8*)(C + (size_t)(m0 + row) * D_ + n0 + wn + ch * 8) = v;
    }
}

// ---------------- LayerNorm over D=384, wave per row ----------------
__global__ __launch_bounds__(256) void ln_kernel(const __bf16* __restrict__ X,
                                                 const float* __restrict__ g,
                                                 const float* __restrict__ bb,
                                                 __bf16* __restrict__ Y)
{
    int row  = blockIdx.x * 4 + (threadIdx.x >> 6);
    int lane = threadIdx.x & 63;
    const __bf16* xr = X + (size_t)row * D_;
    float v[6], s = 0.f, sq = 0.f;
#pragma unroll
    for (int i = 0; i < 6; i++) {
        v[i] = (float)xr[lane + i * 64];
        s += v[i]; sq += v[i] * v[i];
    }
#pragma unroll
    for (int off = 32; off; off >>= 1) { s += __shfl_down(s, off); sq += __shfl_down(sq, off); }
    s = __shfl(s, 0); sq = __shfl(sq, 0);
    float mean = s * (1.f / D_);
    float var  = sq * (1.f / D_) - mean * mean;
    float inv  = rsqrtf(var + 1e-5f);
    __bf16* yr = Y + (size_t)row * D_;
#pragma unroll
    for (int i = 0; i < 6; i++) {
        int c = lane + i * 64;
        yr[c] = (__bf16)((v[i] - mean) * inv * g[c] + bb[c]);
    }
}

// ---------------- linear head D->1, wave per row ----------------
__global__ __launch_bounds__(256) void head_kernel(const __bf16* __restrict__ X,
                                                   const float* __restrict__ w,
                                                   const float* __restrict__ bb,
                                                   float* __restrict__ out)
{
    int row  = blockIdx.x * 4 + (threadIdx.x >> 6);
    int lane = threadIdx.x & 63;
    const __bf16* xr = X + (size_t)row * D_;
    float s = 0.f;
#pragma unroll
    for (int i = 0; i < 6; i++) { int c = lane + i * 64; s += (float)xr[c] * w[c]; }
#pragma unroll
    for (int off = 32; off; off >>= 1) s += __shfl_down(s, off);
    if (lane == 0) out[row] = s + bb[0];
}

// ---------------- cumsum of durations, wave per batch ----------------
__global__ __launch_bounds__(64) void cum_kernel(const int* __restrict__ dur,
                                                 int* __restrict__ cum)
{
    int b = blockIdx.x, lane = threadIdx.x;
    const int* db = dur + b * L_;
    int v[8], s = 0;
#pragma unroll
    for (int i = 0; i < 8; i++) { v[i] = db[lane * 8 + i]; s += v[i]; }
    int ex = s;
#pragma unroll
    for (int off = 1; off < 64; off <<= 1) {
        int n = __shfl_up(ex, off);
        if (lane >= off) ex += n;
    }
    ex -= s;
    int c = ex;
    int* cb = cum + b * L_;
#pragma unroll
    for (int i = 0; i < 8; i++) { c += v[i]; cb[lane * 8 + i] = c; }
}

// ---------------- gather / length-regulate, block per frame ----------------
__global__ __launch_bounds__(128) void gather_kernel(const float* __restrict__ x,
                                                     const int* __restrict__ cum,
                                                     float* __restrict__ out, int T)
{
    int fr = blockIdx.x;
    int b  = fr / T;
    int t  = fr - b * T;
    int tid = threadIdx.x;
    const int* cb = cum + b * L_;
    int total = cb[L_ - 1];
    float4 val = make_float4(0.f, 0.f, 0.f, 0.f);
    if (t < total) {
        int lo = 0, hi = L_;
        while (lo < hi) { int mid = (lo + hi) >> 1; if (cb[mid] > t) hi = mid; else lo = mid + 1; }
        if (tid < 96) val = *(const float4*)(x + ((size_t)(b * L_ + lo)) * D_ + tid * 4);
    }
    if (tid < 96) *(float4*)(out + (size_t)fr * D_ + tid * 4) = val;
}

extern "C" void kernel_launch(void* const* d_in, const int* in_sizes, int n_in,
                              void* d_out, int out_size, void* d_ws, size_t ws_size,
                              hipStream_t stream) {
    const float* x       = (const float*)d_in[0];
    const int*   dur     = (const int*)d_in[1];
    const float* c1a_w   = (const float*)d_in[2];
    const float* c1a_b   = (const float*)d_in[3];
    const float* c1b_w   = (const float*)d_in[4];
    const float* c1b_b   = (const float*)d_in[5];
    const float* ln1_g   = (const float*)d_in[6];
    const float* ln1_b   = (const float*)d_in[7];
    const float* c2a_w   = (const float*)d_in[8];
    const float* c2a_b   = (const float*)d_in[9];
    const float* c2b_w   = (const float*)d_in[10];
    const float* c2b_b   = (const float*)d_in[11];
    const float* ln2_g   = (const float*)d_in[12];
    const float* ln2_b   = (const float*)d_in[13];
    const float* lin_w   = (const float*)d_in[14];
    const float* lin_b   = (const float*)d_in[15];

    const int T = (out_size - B_ * L_) / (B_ * D_);
    float* out_gather = (float*)d_out;
    float* out_dur    = (float*)d_out + (size_t)B_ * T * D_;

    // workspace layout; +4096 guard so A-row -1 (first sequence) stays in-bounds
    char* p = (char*)d_ws + 4096;
    __bf16* xb  = (__bf16*)p; p += (size_t)M_ * D_ * 2;
    __bf16* h1  = (__bf16*)p; p += (size_t)M_ * D_ * 2;
    __bf16* h2  = (__bf16*)p; p += (size_t)M_ * D_ * 2;
    __bf16* w1a = (__bf16*)p; p += (size_t)D_ * KTOT * 2;   // also guards h2 row M_
    __bf16* w1b = (__bf16*)p; p += (size_t)D_ * KTOT * 2;
    __bf16* w2a = (__bf16*)p; p += (size_t)D_ * KTOT * 2;
    __bf16* w2b = (__bf16*)p; p += (size_t)D_ * KTOT * 2;
    int* cum = (int*)p; p += (size_t)B_ * L_ * 4;

    // LR path (independent of predictor chain)
    cum_kernel<<<B_, 64, 0, stream>>>(dur, cum);
    gather_kernel<<<B_ * T, 128, 0, stream>>>(x, cum, out_gather, T);

    // predictor chain
    cvt_kernel<<<(M_ * D_ / 4 + 255) / 256, 256, 0, stream>>>(x, xb, M_ * D_ / 4);
    dim3 rpgrid((D_ * KTOT + 255) / 256, 4);
    repack4_kernel<<<rpgrid, 256, 0, stream>>>(c1a_w, c1b_w, c2a_w, c2b_w, w1a, w1b, w2a, w2b);

    dim3 ggrid(M_ / BM, D_ / BN);  // 256 x 3 = 768 blocks
    conv_gemm<<<ggrid, 128, 0, stream>>>(xb, w1a, c1a_b, h1);
    conv_gemm<<<ggrid, 128, 0, stream>>>(h1, w1b, c1b_b, h2);
    ln_kernel<<<M_ / 4, 256, 0, stream>>>(h2, ln1_g, ln1_b, xb);
    conv_gemm<<<ggrid, 128, 0, stream>>>(xb, w2a, c2a_b, h1);
    conv_gemm<<<ggrid, 128, 0, stream>>>(h1, w2b, c2b_b, h2);
    ln_kernel<<<M_ / 4, 256, 0, stream>>>(h2, ln2_g, ln2_b, xb);
    head_kernel<<<M_ / 4, 256, 0, stream>>>(xb, lin_w, lin_b, out_dur);
}

// Round 5
// 314.505 us; speedup vs baseline: 1.3220x; 1.3220x over previous
//
#include <hip/hip_runtime.h>

#define B_   32
#define L_   512
#define D_   384
#define M_   (B_*L_)    // 16384 rows
#define KTOT (D_*3)     // 1152 GEMM K

typedef __bf16 bf16x8 __attribute__((ext_vector_type(8)));
typedef float  floatx4 __attribute__((ext_vector_type(4)));

// ---------------- conversion: x fp32 -> bf16 ----------------
__global__ __launch_bounds__(256) void cvt_kernel(const float* __restrict__ x,
                                                  __bf16* __restrict__ xb, int n4)
{
    int i = blockIdx.x * 256 + threadIdx.x;
    if (i >= n4) return;
    const float4 v = ((const float4*)x)[i];
    __bf16* o = xb + (size_t)i * 4;
    o[0] = (__bf16)v.x; o[1] = (__bf16)v.y; o[2] = (__bf16)v.z; o[3] = (__bf16)v.w;
}

// ---------------- weight repack: fragment-major for MFMA B-operand ----------------
// w[o][i][k] fp32 -> W3 such that a B-fragment load (n-tile t of 16 cols,
// k-chunk c of 32) is ONE contiguous 1KB block:
//   W3[((t*36 + c)*64 + lane)*8 + j] = w[o = t*16 + (lane&15)]
//                                       [kflat = c*32 + (lane>>4)*8 + j]
// with kflat = s*384 + i  (s = tap, i = input channel).
__global__ __launch_bounds__(256) void repack4_kernel(const float* __restrict__ wa,
                                                      const float* __restrict__ wb,
                                                      const float* __restrict__ wc,
                                                      const float* __restrict__ wd,
                                                      __bf16* __restrict__ oa,
                                                      __bf16* __restrict__ ob,
                                                      __bf16* __restrict__ oc,
                                                      __bf16* __restrict__ od)
{
    int idx = blockIdx.x * 256 + threadIdx.x;
    if (idx >= D_ * KTOT) return;
    const float* w; __bf16* o_;
    switch (blockIdx.y) {
        case 0:  w = wa; o_ = oa; break;
        case 1:  w = wb; o_ = ob; break;
        case 2:  w = wc; o_ = oc; break;
        default: w = wd; o_ = od; break;
    }
    int j  = idx & 7;
    int l  = (idx >> 3) & 63;
    int tc = idx >> 9;          // t*36 + c
    int t  = tc / 36;
    int c  = tc - t * 36;
    int o  = t * 16 + (l & 15);
    int kflat = c * 32 + (l >> 4) * 8 + j;
    int s  = kflat / D_;
    int i  = kflat - s * D_;
    o_[idx] = (__bf16)w[(o * D_ + i) * 3 + s];
}

// ---------------- conv-as-GEMM: barrier-free K-loop ----------------
// C = relu(shiftA @ W^T + bias). BM=64, BN=128, 2 waves (wave-tile 64x64,
// waves split n). The full 66-row A halo (all 384 cols) is staged to LDS
// ONCE (51.7KB, 3 blocks/CU = 155KB), then the 36-step K-loop runs with no
// barriers: 4 ds_read_b128 + 4 coalesced 1KB global B loads + 16 MFMA per
// step. grid = 256 x 3 = 768 = exactly 3 blocks/CU.
#define BM 64
#define BN 128
#define LDA 392   // A LDS row stride in elems (784B = 16*49: aligned, 2-way bank alias only)

__global__ __launch_bounds__(128, 2) void conv_gemm(const __bf16* __restrict__ A,
                                                    const __bf16* __restrict__ W3,
                                                    const float* __restrict__ bias,
                                                    __bf16* __restrict__ C)
{
    __shared__ __bf16 smem[66 * LDA];     // A halo; reused as Cs in epilogue

    const int m0 = blockIdx.x * BM;
    const int n0 = blockIdx.y * BN;
    const int l0 = m0 & 511;              // row within sequence (64 | 512)
    const int b0 = m0 - l0;               // sequence base row

    const int tid  = threadIdx.x;
    const int wave = tid >> 6;
    const int lane = tid & 63;
    const int wn   = wave * 64;
    const int quad = lane >> 4;
    const int lx   = lane & 15;

    // ---- stage A halo rows l0-1 .. l0+64, zero outside sequence ----
    {
        bf16x8 kz;
#pragma unroll
        for (int z = 0; z < 8; z++) kz[z] = (__bf16)0.f;
        for (int c = tid; c < 66 * 48; c += 128) {       // 16B chunks, row-major
            int r = c / 48, q = c - r * 48;
            int l = l0 - 1 + r;
            bf16x8 v = kz;
            if ((unsigned)l < (unsigned)L_)
                v = *(const bf16x8*)(A + (size_t)(b0 + l) * D_ + q * 8);
            *(bf16x8*)(&smem[r * LDA + q * 8]) = v;
        }
    }
    __syncthreads();

    floatx4 acc[4][4];
#pragma unroll
    for (int mi = 0; mi < 4; mi++)
#pragma unroll
        for (int ni = 0; ni < 4; ni++)
#pragma unroll
            for (int r = 0; r < 4; r++) acc[mi][ni][r] = 0.f;

    // B fragment base pointers: tile t0+ni, per-lane 16B slot
    const int t0 = (n0 + wn) >> 4;
    const char* pb[4];
#pragma unroll
    for (int ni = 0; ni < 4; ni++)
        pb[ni] = (const char*)W3 + ((size_t)(t0 + ni) * 36 * 64 + lane) * 16;

    const __bf16* asb = &smem[lx * LDA + quad * 8];      // per-lane A base

    // ---- barrier-free K loop: 12 i-chunks x 3 taps ----
#pragma unroll
    for (int it = 0; it < 12; it++) {
#pragma unroll
        for (int s = 0; s < 3; s++) {
            const int cofs = (s * 12 + it) * 1024;       // B byte offset for chunk
            bf16x8 af[4], bg[4];
#pragma unroll
            for (int ni = 0; ni < 4; ni++)
                bg[ni] = *(const bf16x8*)(pb[ni] + cofs);
#pragma unroll
            for (int mi = 0; mi < 4; mi++)
                af[mi] = *(const bf16x8*)(asb + (mi * 16 + s) * LDA + it * 32);
#pragma unroll
            for (int mi = 0; mi < 4; mi++)
#pragma unroll
                for (int ni = 0; ni < 4; ni++)
                    acc[mi][ni] = __builtin_amdgcn_mfma_f32_16x16x32_bf16(af[mi], bg[ni], acc[mi][ni], 0, 0, 0);
        }
    }

    // ---- epilogue: bias+relu -> LDS transpose -> coalesced 16B stores ----
    __syncthreads();                       // done reading A halo
    __bf16* Cs = smem;                     // 64 x 136 stride
#pragma unroll
    for (int mi = 0; mi < 4; mi++) {
#pragma unroll
        for (int ni = 0; ni < 4; ni++) {
            int col = wn + ni * 16 + lx;
            float bv = bias[n0 + col];
#pragma unroll
            for (int r = 0; r < 4; r++) {
                int row = mi * 16 + quad * 4 + r;
                float v = acc[mi][ni][r] + bv;
                v = v > 0.f ? v : 0.f;
                Cs[row * 136 + col] = (__bf16)v;
            }
        }
    }
    __syncthreads();
    for (int c = tid; c < 64 * 16; c += 128) {
        int row = c >> 4, q = c & 15;
        bf16x8 v = *(const bf16x8*)(&Cs[row * 136 + q * 8]);
        *(bf16x8*)(C + (size_t)(m0 + row) * D_ + n0 + q * 8) = v;
    }
}

// ---------------- LayerNorm over D=384, wave per row ----------------
__global__ __launch_bounds__(256) void ln_kernel(const __bf16* __restrict__ X,
                                                 const float* __restrict__ g,
                                                 const float* __restrict__ bb,
                                                 __bf16* __restrict__ Y)
{
    int row  = blockIdx.x * 4 + (threadIdx.x >> 6);
    int lane = threadIdx.x & 63;
    const __bf16* xr = X + (size_t)row * D_;
    float v[6], s = 0.f, sq = 0.f;
#pragma unroll
    for (int i = 0; i < 6; i++) {
        v[i] = (float)xr[lane + i * 64];
        s += v[i]; sq += v[i] * v[i];
    }
#pragma unroll
    for (int off = 32; off; off >>= 1) { s += __shfl_down(s, off); sq += __shfl_down(sq, off); }
    s = __shfl(s, 0); sq = __shfl(sq, 0);
    float mean = s * (1.f / D_);
    float var  = sq * (1.f / D_) - mean * mean;
    float inv  = rsqrtf(var + 1e-5f);
    __bf16* yr = Y + (size_t)row * D_;
#pragma unroll
    for (int i = 0; i < 6; i++) {
        int c = lane + i * 64;
        yr[c] = (__bf16)((v[i] - mean) * inv * g[c] + bb[c]);
    }
}

// ---------------- linear head D->1, wave per row ----------------
__global__ __launch_bounds__(256) void head_kernel(const __bf16* __restrict__ X,
                                                   const float* __restrict__ w,
                                                   const float* __restrict__ bb,
                                                   float* __restrict__ out)
{
    int row  = blockIdx.x * 4 + (threadIdx.x >> 6);
    int lane = threadIdx.x & 63;
    const __bf16* xr = X + (size_t)row * D_;
    float s = 0.f;
#pragma unroll
    for (int i = 0; i < 6; i++) { int c = lane + i * 64; s += (float)xr[c] * w[c]; }
#pragma unroll
    for (int off = 32; off; off >>= 1) s += __shfl_down(s, off);
    if (lane == 0) out[row] = s + bb[0];
}

// ---------------- cumsum of durations, wave per batch ----------------
__global__ __launch_bounds__(64) void cum_kernel(const int* __restrict__ dur,
                                                 int* __restrict__ cum)
{
    int b = blockIdx.x, lane = threadIdx.x;
    const int* db = dur + b * L_;
    int v[8], s = 0;
#pragma unroll
    for (int i = 0; i < 8; i++) { v[i] = db[lane * 8 + i]; s += v[i]; }
    int ex = s;
#pragma unroll
    for (int off = 1; off < 64; off <<= 1) {
        int n = __shfl_up(ex, off);
        if (lane >= off) ex += n;
    }
    ex -= s;
    int c = ex;
    int* cb = cum + b * L_;
#pragma unroll
    for (int i = 0; i < 8; i++) { c += v[i]; cb[lane * 8 + i] = c; }
}

// ---------------- gather / length-regulate, block per frame ----------------
__global__ __launch_bounds__(128) void gather_kernel(const float* __restrict__ x,
                                                     const int* __restrict__ cum,
                                                     float* __restrict__ out, int T)
{
    int fr = blockIdx.x;
    int b  = fr / T;
    int t  = fr - b * T;
    int tid = threadIdx.x;
    const int* cb = cum + b * L_;
    int total = cb[L_ - 1];
    float4 val = make_float4(0.f, 0.f, 0.f, 0.f);
    if (t < total) {
        int lo = 0, hi = L_;
        while (lo < hi) { int mid = (lo + hi) >> 1; if (cb[mid] > t) hi = mid; else lo = mid + 1; }
        if (tid < 96) val = *(const float4*)(x + ((size_t)(b * L_ + lo)) * D_ + tid * 4);
    }
    if (tid < 96) *(float4*)(out + (size_t)fr * D_ + tid * 4) = val;
}

extern "C" void kernel_launch(void* const* d_in, const int* in_sizes, int n_in,
                              void* d_out, int out_size, void* d_ws, size_t ws_size,
                              hipStream_t stream) {
    const float* x       = (const float*)d_in[0];
    const int*   dur     = (const int*)d_in[1];
    const float* c1a_w   = (const float*)d_in[2];
    const float* c1a_b   = (const float*)d_in[3];
    const float* c1b_w   = (const float*)d_in[4];
    const float* c1b_b   = (const float*)d_in[5];
    const float* ln1_g   = (const float*)d_in[6];
    const float* ln1_b   = (const float*)d_in[7];
    const float* c2a_w   = (const float*)d_in[8];
    const float* c2a_b   = (const float*)d_in[9];
    const float* c2b_w   = (const float*)d_in[10];
    const float* c2b_b   = (const float*)d_in[11];
    const float* ln2_g   = (const float*)d_in[12];
    const float* ln2_b   = (const float*)d_in[13];
    const float* lin_w   = (const float*)d_in[14];
    const float* lin_b   = (const float*)d_in[15];

    const int T = (out_size - B_ * L_) / (B_ * D_);
    float* out_gather = (float*)d_out;
    float* out_dur    = (float*)d_out + (size_t)B_ * T * D_;

    // workspace layout
    char* p = (char*)d_ws;
    __bf16* xb  = (__bf16*)p; p += (size_t)M_ * D_ * 2;
    __bf16* h1  = (__bf16*)p; p += (size_t)M_ * D_ * 2;
    __bf16* h2  = (__bf16*)p; p += (size_t)M_ * D_ * 2;
    __bf16* w1a = (__bf16*)p; p += (size_t)D_ * KTOT * 2;
    __bf16* w1b = (__bf16*)p; p += (size_t)D_ * KTOT * 2;
    __bf16* w2a = (__bf16*)p; p += (size_t)D_ * KTOT * 2;
    __bf16* w2b = (__bf16*)p; p += (size_t)D_ * KTOT * 2;
    int* cum = (int*)p; p += (size_t)B_ * L_ * 4;

    // LR path (independent of predictor chain)
    cum_kernel<<<B_, 64, 0, stream>>>(dur, cum);
    gather_kernel<<<B_ * T, 128, 0, stream>>>(x, cum, out_gather, T);

    // predictor chain
    cvt_kernel<<<(M_ * D_ / 4 + 255) / 256, 256, 0, stream>>>(x, xb, M_ * D_ / 4);
    dim3 rpgrid((D_ * KTOT + 255) / 256, 4);
    repack4_kernel<<<rpgrid, 256, 0, stream>>>(c1a_w, c1b_w, c2a_w, c2b_w, w1a, w1b, w2a, w2b);

    dim3 ggrid(M_ / BM, D_ / BN);  // 256 x 3 = 768 blocks = 3 per CU
    conv_gemm<<<ggrid, 128, 0, stream>>>(xb, w1a, c1a_b, h1);
    conv_gemm<<<ggrid, 128, 0, stream>>>(h1, w1b, c1b_b, h2);
    ln_kernel<<<M_ / 4, 256, 0, stream>>>(h2, ln1_g, ln1_b, xb);
    conv_gemm<<<ggrid, 128, 0, stream>>>(xb, w2a, c2a_b, h1);
    conv_gemm<<<ggrid, 128, 0, stream>>>(h1, w2b, c2b_b, h2);
    ln_kernel<<<M_ / 4, 256, 0, stream>>>(h2, ln2_g, ln2_b, xb);
    head_kernel<<<M_ / 4, 256, 0, stream>>>(xb, lin_w, lin_b, out_dur);
}

// Round 6
// 294.160 us; speedup vs baseline: 1.4135x; 1.0692x over previous
//
#include <hip/hip_runtime.h>

#define B_   32
#define L_   512
#define D_   384
#define M_   (B_*L_)    // 16384 rows
#define KTOT (D_*3)     // 1152 GEMM K

typedef __bf16 bf16x8 __attribute__((ext_vector_type(8)));
typedef float  floatx4 __attribute__((ext_vector_type(4)));

// ---------------- conversion: x fp32 -> bf16 ----------------
__global__ __launch_bounds__(256) void cvt_kernel(const float* __restrict__ x,
                                                  __bf16* __restrict__ xb, int n4)
{
    int i = blockIdx.x * 256 + threadIdx.x;
    if (i >= n4) return;
    const float4 v = ((const float4*)x)[i];
    __bf16* o = xb + (size_t)i * 4;
    o[0] = (__bf16)v.x; o[1] = (__bf16)v.y; o[2] = (__bf16)v.z; o[3] = (__bf16)v.w;
}

// ---------------- weight repack: chunk-major fragment layout ----------------
// w[o][i][k] fp32 -> W3 s.t. the B-fragment for (k-chunk c, n-tile t) is ONE
// contiguous 1KB block, and consecutive c are +24KB apart (uniform K-loop bump):
//   W3[((c*24 + t)*64 + lane)*8 + j] = w[o = t*16 + (lane&15)]
//                                       [kflat = c*32 + (lane>>4)*8 + j]
// kflat = s*384 + i (s = tap, i = input channel).
__global__ __launch_bounds__(256) void repack4_kernel(const float* __restrict__ wa,
                                                      const float* __restrict__ wb,
                                                      const float* __restrict__ wc,
                                                      const float* __restrict__ wd,
                                                      __bf16* __restrict__ oa,
                                                      __bf16* __restrict__ ob,
                                                      __bf16* __restrict__ oc,
                                                      __bf16* __restrict__ od)
{
    int idx = blockIdx.x * 256 + threadIdx.x;
    if (idx >= D_ * KTOT) return;
    const float* w; __bf16* o_;
    switch (blockIdx.y) {
        case 0:  w = wa; o_ = oa; break;
        case 1:  w = wb; o_ = ob; break;
        case 2:  w = wc; o_ = oc; break;
        default: w = wd; o_ = od; break;
    }
    int j  = idx & 7;
    int l  = (idx >> 3) & 63;
    int ct = idx >> 9;          // c*24 + t
    int c  = ct / 24;
    int t  = ct - c * 24;
    int o  = t * 16 + (l & 15);
    int kflat = c * 32 + (l >> 4) * 8 + j;
    int s  = kflat / D_;
    int i  = kflat - s * D_;
    o_[idx] = (__bf16)w[(o * D_ + i) * 3 + s];
}

// ---------------- conv-as-GEMM: software-pipelined barrier-free K-loop ----------------
// C = relu(shiftA @ W^T + bias). BM=64, BN=128, 2 waves (wave-tile 64x64).
// A halo (66 rows x 384) staged to LDS once; 36-step K-loop with explicit
// register pipeline: B prefetched 2 steps ahead (3 bufs, ~L2 latency), A one
// step ahead (2 bufs). grid = 256x3 = 768 = exactly 3 blocks/CU.
#define BM 64
#define BN 128
#define LDA 392   // A LDS row stride in elems (784B: 16B-aligned, 2-way bank alias only)

__global__ __launch_bounds__(128, 2) void conv_gemm(const __bf16* __restrict__ A,
                                                    const __bf16* __restrict__ W3,
                                                    const float* __restrict__ bias,
                                                    __bf16* __restrict__ C)
{
    __shared__ __bf16 smem[66 * LDA];     // A halo; reused as Cs in epilogue

    const int m0 = blockIdx.x * BM;
    const int n0 = blockIdx.y * BN;
    const int l0 = m0 & 511;              // row within sequence (64 | 512)
    const int b0 = m0 - l0;               // sequence base row

    const int tid  = threadIdx.x;
    const int wave = tid >> 6;
    const int lane = tid & 63;
    const int wn   = wave * 64;
    const int quad = lane >> 4;
    const int lx   = lane & 15;

    // ---- stage A halo rows l0-1 .. l0+64, zero outside sequence ----
    {
        bf16x8 kz;
#pragma unroll
        for (int z = 0; z < 8; z++) kz[z] = (__bf16)0.f;
        for (int c = tid; c < 66 * 48; c += 128) {       // 16B chunks, row-major
            int r = c / 48, q = c - r * 48;
            int l = l0 - 1 + r;
            bf16x8 v = kz;
            if ((unsigned)l < (unsigned)L_)
                v = *(const bf16x8*)(A + (size_t)(b0 + l) * D_ + q * 8);
            *(bf16x8*)(&smem[r * LDA + q * 8]) = v;
        }
    }
    __syncthreads();

    floatx4 acc[4][4];
#pragma unroll
    for (int mi = 0; mi < 4; mi++)
#pragma unroll
        for (int ni = 0; ni < 4; ni++)
#pragma unroll
            for (int r = 0; r < 4; r++) acc[mi][ni][r] = 0.f;

    // B fragment bases: tile t0+ni, per-lane 16B slot; step c adds c*24576B.
    const int t0 = (n0 + wn) >> 4;
    const char* pb[4];
#pragma unroll
    for (int ni = 0; ni < 4; ni++)
        pb[ni] = (const char*)W3 + ((size_t)(t0 + ni) * 64 + lane) * 16;

    const __bf16* asb = &smem[lx * LDA + quad * 8];      // per-lane A base

    // ---- register pipeline: af 2-deep (LDS), bg 3-deep (global/L2) ----
    bf16x8 af[2][4], bg[3][4];
    auto loadA = [&](int buf, int c) {
        const int s = c / 12, it = c - s * 12;           // kflat = s*384 + it*32
#pragma unroll
        for (int mi = 0; mi < 4; mi++)
            af[buf][mi] = *(const bf16x8*)(asb + (mi * 16 + s) * LDA + it * 32);
    };
    auto loadB = [&](int buf, int c) {
#pragma unroll
        for (int ni = 0; ni < 4; ni++)
            bg[buf][ni] = *(const bf16x8*)(pb[ni] + (size_t)c * 24576);
    };

    loadB(0, 0); loadB(1, 1); loadA(0, 0);

#pragma unroll
    for (int c = 0; c < 36; c++) {
        const int c2 = c & 1, c3 = c % 3;
        if (c + 1 < 36) loadA((c + 1) & 1, c + 1);
        if (c + 2 < 36) loadB((c + 2) % 3, c + 2);
#pragma unroll
        for (int mi = 0; mi < 4; mi++)
#pragma unroll
            for (int ni = 0; ni < 4; ni++)
                acc[mi][ni] = __builtin_amdgcn_mfma_f32_16x16x32_bf16(af[c2][mi], bg[c3][ni], acc[mi][ni], 0, 0, 0);
    }

    // ---- epilogue: bias+relu -> LDS transpose -> coalesced 16B stores ----
    __syncthreads();                       // both waves done reading A halo
    __bf16* Cs = smem;                     // 64 x 136 stride
#pragma unroll
    for (int mi = 0; mi < 4; mi++) {
#pragma unroll
        for (int ni = 0; ni < 4; ni++) {
            int col = wn + ni * 16 + lx;
            float bv = bias[n0 + col];
#pragma unroll
            for (int r = 0; r < 4; r++) {
                int row = mi * 16 + quad * 4 + r;
                float v = acc[mi][ni][r] + bv;
                v = v > 0.f ? v : 0.f;
                Cs[row * 136 + col] = (__bf16)v;
            }
        }
    }
    __syncthreads();
    for (int c = tid; c < 64 * 16; c += 128) {
        int row = c >> 4, q = c & 15;
        bf16x8 v = *(const bf16x8*)(&Cs[row * 136 + q * 8]);
        *(bf16x8*)(C + (size_t)(m0 + row) * D_ + n0 + q * 8) = v;
    }
}

// ---------------- LayerNorm over D=384, wave per row ----------------
__global__ __launch_bounds__(256) void ln_kernel(const __bf16* __restrict__ X,
                                                 const float* __restrict__ g,
                                                 const float* __restrict__ bb,
                                                 __bf16* __restrict__ Y)
{
    int row  = blockIdx.x * 4 + (threadIdx.x >> 6);
    int lane = threadIdx.x & 63;
    const __bf16* xr = X + (size_t)row * D_;
    float v[6], s = 0.f, sq = 0.f;
#pragma unroll
    for (int i = 0; i < 6; i++) {
        v[i] = (float)xr[lane + i * 64];
        s += v[i]; sq += v[i] * v[i];
    }
#pragma unroll
    for (int off = 32; off; off >>= 1) { s += __shfl_down(s, off); sq += __shfl_down(sq, off); }
    s = __shfl(s, 0); sq = __shfl(sq, 0);
    float mean = s * (1.f / D_);
    float var  = sq * (1.f / D_) - mean * mean;
    float inv  = rsqrtf(var + 1e-5f);
    __bf16* yr = Y + (size_t)row * D_;
#pragma unroll
    for (int i = 0; i < 6; i++) {
        int c = lane + i * 64;
        yr[c] = (__bf16)((v[i] - mean) * inv * g[c] + bb[c]);
    }
}

// ---------------- linear head D->1, wave per row ----------------
__global__ __launch_bounds__(256) void head_kernel(const __bf16* __restrict__ X,
                                                   const float* __restrict__ w,
                                                   const float* __restrict__ bb,
                                                   float* __restrict__ out)
{
    int row  = blockIdx.x * 4 + (threadIdx.x >> 6);
    int lane = threadIdx.x & 63;
    const __bf16* xr = X + (size_t)row * D_;
    float s = 0.f;
#pragma unroll
    for (int i = 0; i < 6; i++) { int c = lane + i * 64; s += (float)xr[c] * w[c]; }
#pragma unroll
    for (int off = 32; off; off >>= 1) s += __shfl_down(s, off);
    if (lane == 0) out[row] = s + bb[0];
}

// ---------------- cumsum of durations, wave per batch ----------------
__global__ __launch_bounds__(64) void cum_kernel(const int* __restrict__ dur,
                                                 int* __restrict__ cum)
{
    int b = blockIdx.x, lane = threadIdx.x;
    const int* db = dur + b * L_;
    int v[8], s = 0;
#pragma unroll
    for (int i = 0; i < 8; i++) { v[i] = db[lane * 8 + i]; s += v[i]; }
    int ex = s;
#pragma unroll
    for (int off = 1; off < 64; off <<= 1) {
        int n = __shfl_up(ex, off);
        if (lane >= off) ex += n;
    }
    ex -= s;
    int c = ex;
    int* cb = cum + b * L_;
#pragma unroll
    for (int i = 0; i < 8; i++) { c += v[i]; cb[lane * 8 + i] = c; }
}

// ---------------- gather / length-regulate, block per frame ----------------
__global__ __launch_bounds__(128) void gather_kernel(const float* __restrict__ x,
                                                     const int* __restrict__ cum,
                                                     float* __restrict__ out, int T)
{
    int fr = blockIdx.x;
    int b  = fr / T;
    int t  = fr - b * T;
    int tid = threadIdx.x;
    const int* cb = cum + b * L_;
    int total = cb[L_ - 1];
    float4 val = make_float4(0.f, 0.f, 0.f, 0.f);
    if (t < total) {
        int lo = 0, hi = L_;
        while (lo < hi) { int mid = (lo + hi) >> 1; if (cb[mid] > t) hi = mid; else lo = mid + 1; }
        if (tid < 96) val = *(const float4*)(x + ((size_t)(b * L_ + lo)) * D_ + tid * 4);
    }
    if (tid < 96) *(float4*)(out + (size_t)fr * D_ + tid * 4) = val;
}

extern "C" void kernel_launch(void* const* d_in, const int* in_sizes, int n_in,
                              void* d_out, int out_size, void* d_ws, size_t ws_size,
                              hipStream_t stream) {
    const float* x       = (const float*)d_in[0];
    const int*   dur     = (const int*)d_in[1];
    const float* c1a_w   = (const float*)d_in[2];
    const float* c1a_b   = (const float*)d_in[3];
    const float* c1b_w   = (const float*)d_in[4];
    const float* c1b_b   = (const float*)d_in[5];
    const float* ln1_g   = (const float*)d_in[6];
    const float* ln1_b   = (const float*)d_in[7];
    const float* c2a_w   = (const float*)d_in[8];
    const float* c2a_b   = (const float*)d_in[9];
    const float* c2b_w   = (const float*)d_in[10];
    const float* c2b_b   = (const float*)d_in[11];
    const float* ln2_g   = (const float*)d_in[12];
    const float* ln2_b   = (const float*)d_in[13];
    const float* lin_w   = (const float*)d_in[14];
    const float* lin_b   = (const float*)d_in[15];

    const int T = (out_size - B_ * L_) / (B_ * D_);
    float* out_gather = (float*)d_out;
    float* out_dur    = (float*)d_out + (size_t)B_ * T * D_;

    // workspace layout
    char* p = (char*)d_ws;
    __bf16* xb  = (__bf16*)p; p += (size_t)M_ * D_ * 2;
    __bf16* h1  = (__bf16*)p; p += (size_t)M_ * D_ * 2;
    __bf16* h2  = (__bf16*)p; p += (size_t)M_ * D_ * 2;
    __bf16* w1a = (__bf16*)p; p += (size_t)D_ * KTOT * 2;
    __bf16* w1b = (__bf16*)p; p += (size_t)D_ * KTOT * 2;
    __bf16* w2a = (__bf16*)p; p += (size_t)D_ * KTOT * 2;
    __bf16* w2b = (__bf16*)p; p += (size_t)D_ * KTOT * 2;
    int* cum = (int*)p; p += (size_t)B_ * L_ * 4;

    // LR path (independent of predictor chain)
    cum_kernel<<<B_, 64, 0, stream>>>(dur, cum);
    gather_kernel<<<B_ * T, 128, 0, stream>>>(x, cum, out_gather, T);

    // predictor chain
    cvt_kernel<<<(M_ * D_ / 4 + 255) / 256, 256, 0, stream>>>(x, xb, M_ * D_ / 4);
    dim3 rpgrid((D_ * KTOT + 255) / 256, 4);
    repack4_kernel<<<rpgrid, 256, 0, stream>>>(c1a_w, c1b_w, c2a_w, c2b_w, w1a, w1b, w2a, w2b);

    dim3 ggrid(M_ / BM, D_ / BN);  // 256 x 3 = 768 blocks = 3 per CU
    conv_gemm<<<ggrid, 128, 0, stream>>>(xb, w1a, c1a_b, h1);
    conv_gemm<<<ggrid, 128, 0, stream>>>(h1, w1b, c1b_b, h2);
    ln_kernel<<<M_ / 4, 256, 0, stream>>>(h2, ln1_g, ln1_b, xb);
    conv_gemm<<<ggrid, 128, 0, stream>>>(xb, w2a, c2a_b, h1);
    conv_gemm<<<ggrid, 128, 0, stream>>>(h1, w2b, c2b_b, h2);
    ln_kernel<<<M_ / 4, 256, 0, stream>>>(h2, ln2_g, ln2_b, xb);
    head_kernel<<<M_ / 4, 256, 0, stream>>>(xb, lin_w, lin_b, out_dur);
}

// Round 7
// 290.285 us; speedup vs baseline: 1.4323x; 1.0133x over previous
//
#include <hip/hip_runtime.h>

#define B_   32
#define L_   512
#define D_   384
#define M_   (B_*L_)    // 16384 rows
#define KTOT (D_*3)     // 1152 GEMM K

typedef __bf16 bf16x8 __attribute__((ext_vector_type(8)));
typedef float  floatx4 __attribute__((ext_vector_type(4)));

// ---------------- weight repack: chunk-major fragment layout ----------------
// w[o][i][k] fp32 -> W3 s.t. the B-fragment for (k-chunk c, n-tile t) is ONE
// contiguous 1KB block; consecutive c are +24KB apart:
//   W3[((c*24 + t)*64 + lane)*8 + j] = w[o = t*16 + (lane&15)]
//                                       [kflat = c*32 + (lane>>4)*8 + j]
// kflat = s*384 + i (s = tap, i = input channel).
__global__ __launch_bounds__(256) void repack4_kernel(const float* __restrict__ wa,
                                                      const float* __restrict__ wb,
                                                      const float* __restrict__ wc,
                                                      const float* __restrict__ wd,
                                                      __bf16* __restrict__ oa,
                                                      __bf16* __restrict__ ob,
                                                      __bf16* __restrict__ oc,
                                                      __bf16* __restrict__ od)
{
    int idx = blockIdx.x * 256 + threadIdx.x;
    if (idx >= D_ * KTOT) return;
    const float* w; __bf16* o_;
    switch (blockIdx.y) {
        case 0:  w = wa; o_ = oa; break;
        case 1:  w = wb; o_ = ob; break;
        case 2:  w = wc; o_ = oc; break;
        default: w = wd; o_ = od; break;
    }
    int j  = idx & 7;
    int l  = (idx >> 3) & 63;
    int ct = idx >> 9;          // c*24 + t
    int c  = ct / 24;
    int t  = ct - c * 24;
    int o  = t * 16 + (l & 15);
    int kflat = c * 32 + (l >> 4) * 8 + j;
    int s  = kflat / D_;
    int i  = kflat - s * D_;
    o_[idx] = (__bf16)w[(o * D_ + i) * 3 + s];
}

// ---------------- conv-as-GEMM: 12 waves/CU, 2-phase A halo in LDS ----------------
// C = relu(shiftA @ W^T + bias). BM=64, BN=64, 2 waves (wave tile 64x32).
// A halo (66 rows) staged in two 192-col phases (26.4KB LDS -> 6 blocks/CU =
// 12 waves/CU). K-loop barrier-free within a phase; B register-pipelined
// 2 steps ahead. grid = 256 x 6 = 1536 blocks = exactly 6 per CU.
// CVT: if true, A is fp32 (the original x) and is converted during staging.
#define BM 64
#define BN 64
#define LDW 200   // LDS row stride in bf16 elems (400B, 16B-aligned)

template<bool CVT>
__global__ __launch_bounds__(128, 3) void conv_gemm(const void* __restrict__ Av,
                                                    const __bf16* __restrict__ W3,
                                                    const float* __restrict__ bias,
                                                    __bf16* __restrict__ C)
{
    __shared__ __bf16 smem[66 * LDW];     // A halo phase window; Cs in epilogue

    const int m0 = blockIdx.x * BM;
    const int n0 = blockIdx.y * BN;
    const int l0 = m0 & 511;              // row within sequence (64 | 512)
    const int b0 = m0 - l0;               // sequence base row

    const int tid  = threadIdx.x;
    const int wave = tid >> 6;
    const int lane = tid & 63;
    const int wn   = wave * 32;
    const int quad = lane >> 4;
    const int lx   = lane & 15;

    floatx4 acc[4][2];
#pragma unroll
    for (int mi = 0; mi < 4; mi++)
#pragma unroll
        for (int ni = 0; ni < 2; ni++)
#pragma unroll
            for (int r = 0; r < 4; r++) acc[mi][ni][r] = 0.f;

    // B fragment bases: wave covers tiles t0+2w, t0+2w+1; step c adds c*24576B.
    const int t0 = (n0 >> 4) + 2 * wave;
    const char* pb[2];
#pragma unroll
    for (int ni = 0; ni < 2; ni++)
        pb[ni] = (const char*)W3 + ((size_t)(t0 + ni) * 64 + lane) * 16;

    bf16x8 bg[3][2];
    auto loadB = [&](int buf, int c) {
#pragma unroll
        for (int ni = 0; ni < 2; ni++)
            bg[buf][ni] = *(const bf16x8*)(pb[ni] + (size_t)c * 24576);
    };
    // linear step n = ph*18 + itl*3 + s  ->  W3 chunk c = s*12 + ph*6 + itl
    auto cIdx = [](int n) {
        int ph = n / 18, r = n - ph * 18, itl = r / 3, s = r - itl * 3;
        return s * 12 + ph * 6 + itl;
    };

    loadB(0, cIdx(0));
    loadB(1, cIdx(1));

    const __bf16* asb = &smem[lx * LDW + quad * 8];   // per-lane A base

#pragma unroll
    for (int ph = 0; ph < 2; ph++) {
        // ---- stage A halo rows l0-1 .. l0+64, cols [ph*192, ph*192+192) ----
        if (ph) __syncthreads();          // all waves done reading phase 0
        {
            bf16x8 kz;
#pragma unroll
            for (int z = 0; z < 8; z++) kz[z] = (__bf16)0.f;
            for (int c = tid; c < 66 * 24; c += 128) {
                int r = c / 24, q = c - r * 24;
                int l = l0 - 1 + r;
                bf16x8 v = kz;
                if ((unsigned)l < (unsigned)L_) {
                    if (CVT) {
                        const float* xr = (const float*)Av + (size_t)(b0 + l) * D_ + ph * 192 + q * 8;
                        const float4 f0 = *(const float4*)xr;
                        const float4 f1 = *(const float4*)(xr + 4);
                        v[0] = (__bf16)f0.x; v[1] = (__bf16)f0.y;
                        v[2] = (__bf16)f0.z; v[3] = (__bf16)f0.w;
                        v[4] = (__bf16)f1.x; v[5] = (__bf16)f1.y;
                        v[6] = (__bf16)f1.z; v[7] = (__bf16)f1.w;
                    } else {
                        v = *(const bf16x8*)((const __bf16*)Av + (size_t)(b0 + l) * D_ + ph * 192 + q * 8);
                    }
                }
                *(bf16x8*)(&smem[r * LDW + q * 8]) = v;
            }
        }
        __syncthreads();

        // ---- 18 barrier-free K-steps in this phase ----
#pragma unroll
        for (int nl = 0; nl < 18; nl++) {
            const int n   = ph * 18 + nl;
            const int itl = nl / 3, s = nl - itl * 3;
            if (n + 2 < 36) loadB((n + 2) % 3, cIdx(n + 2));
            bf16x8 af[4];
#pragma unroll
            for (int mi = 0; mi < 4; mi++)
                af[mi] = *(const bf16x8*)(asb + (mi * 16 + s) * LDW + itl * 32);
#pragma unroll
            for (int mi = 0; mi < 4; mi++)
#pragma unroll
                for (int ni = 0; ni < 2; ni++)
                    acc[mi][ni] = __builtin_amdgcn_mfma_f32_16x16x32_bf16(af[mi], bg[n % 3][ni], acc[mi][ni], 0, 0, 0);
        }
    }

    // ---- epilogue: bias+relu -> LDS transpose -> coalesced 16B stores ----
    __syncthreads();                       // done reading A halo
    __bf16* Cs = smem;                     // 64 x 72 stride
#pragma unroll
    for (int mi = 0; mi < 4; mi++) {
#pragma unroll
        for (int ni = 0; ni < 2; ni++) {
            int col = wn + ni * 16 + lx;
            float bv = bias[n0 + col];
#pragma unroll
            for (int r = 0; r < 4; r++) {
                int row = mi * 16 + quad * 4 + r;
                float v = acc[mi][ni][r] + bv;
                v = v > 0.f ? v : 0.f;
                Cs[row * 72 + col] = (__bf16)v;
            }
        }
    }
    __syncthreads();
#pragma unroll
    for (int c = 0; c < 4; c++) {
        int idx = c * 128 + tid;
        int row = idx >> 3, q = idx & 7;
        bf16x8 v = *(const bf16x8*)(&Cs[row * 72 + q * 8]);
        *(bf16x8*)(C + (size_t)(m0 + row) * D_ + n0 + q * 8) = v;
    }
}

// ---------------- LayerNorm over D=384, wave per row ----------------
__global__ __launch_bounds__(256) void ln_kernel(const __bf16* __restrict__ X,
                                                 const float* __restrict__ g,
                                                 const float* __restrict__ bb,
                                                 __bf16* __restrict__ Y)
{
    int row  = blockIdx.x * 4 + (threadIdx.x >> 6);
    int lane = threadIdx.x & 63;
    const __bf16* xr = X + (size_t)row * D_;
    float v[6], s = 0.f, sq = 0.f;
#pragma unroll
    for (int i = 0; i < 6; i++) {
        v[i] = (float)xr[lane + i * 64];
        s += v[i]; sq += v[i] * v[i];
    }
#pragma unroll
    for (int off = 32; off; off >>= 1) { s += __shfl_down(s, off); sq += __shfl_down(sq, off); }
    s = __shfl(s, 0); sq = __shfl(sq, 0);
    float mean = s * (1.f / D_);
    float var  = sq * (1.f / D_) - mean * mean;
    float inv  = rsqrtf(var + 1e-5f);
    __bf16* yr = Y + (size_t)row * D_;
#pragma unroll
    for (int i = 0; i < 6; i++) {
        int c = lane + i * 64;
        yr[c] = (__bf16)((v[i] - mean) * inv * g[c] + bb[c]);
    }
}

// ---------------- linear head D->1, wave per row ----------------
__global__ __launch_bounds__(256) void head_kernel(const __bf16* __restrict__ X,
                                                   const float* __restrict__ w,
                                                   const float* __restrict__ bb,
                                                   float* __restrict__ out)
{
    int row  = blockIdx.x * 4 + (threadIdx.x >> 6);
    int lane = threadIdx.x & 63;
    const __bf16* xr = X + (size_t)row * D_;
    float s = 0.f;
#pragma unroll
    for (int i = 0; i < 6; i++) { int c = lane + i * 64; s += (float)xr[c] * w[c]; }
#pragma unroll
    for (int off = 32; off; off >>= 1) s += __shfl_down(s, off);
    if (lane == 0) out[row] = s + bb[0];
}

// ---------------- cumsum of durations, wave per batch ----------------
__global__ __launch_bounds__(64) void cum_kernel(const int* __restrict__ dur,
                                                 int* __restrict__ cum)
{
    int b = blockIdx.x, lane = threadIdx.x;
    const int* db = dur + b * L_;
    int v[8], s = 0;
#pragma unroll
    for (int i = 0; i < 8; i++) { v[i] = db[lane * 8 + i]; s += v[i]; }
    int ex = s;
#pragma unroll
    for (int off = 1; off < 64; off <<= 1) {
        int n = __shfl_up(ex, off);
        if (lane >= off) ex += n;
    }
    ex -= s;
    int c = ex;
    int* cb = cum + b * L_;
#pragma unroll
    for (int i = 0; i < 8; i++) { c += v[i]; cb[lane * 8 + i] = c; }
}

// ---------------- gather / length-regulate, block per frame ----------------
__global__ __launch_bounds__(128) void gather_kernel(const float* __restrict__ x,
                                                     const int* __restrict__ cum,
                                                     float* __restrict__ out, int T)
{
    int fr = blockIdx.x;
    int b  = fr / T;
    int t  = fr - b * T;
    int tid = threadIdx.x;
    const int* cb = cum + b * L_;
    int total = cb[L_ - 1];
    float4 val = make_float4(0.f, 0.f, 0.f, 0.f);
    if (t < total) {
        int lo = 0, hi = L_;
        while (lo < hi) { int mid = (lo + hi) >> 1; if (cb[mid] > t) hi = mid; else lo = mid + 1; }
        if (tid < 96) val = *(const float4*)(x + ((size_t)(b * L_ + lo)) * D_ + tid * 4);
    }
    if (tid < 96) *(float4*)(out + (size_t)fr * D_ + tid * 4) = val;
}

extern "C" void kernel_launch(void* const* d_in, const int* in_sizes, int n_in,
                              void* d_out, int out_size, void* d_ws, size_t ws_size,
                              hipStream_t stream) {
    const float* x       = (const float*)d_in[0];
    const int*   dur     = (const int*)d_in[1];
    const float* c1a_w   = (const float*)d_in[2];
    const float* c1a_b   = (const float*)d_in[3];
    const float* c1b_w   = (const float*)d_in[4];
    const float* c1b_b   = (const float*)d_in[5];
    const float* ln1_g   = (const float*)d_in[6];
    const float* ln1_b   = (const float*)d_in[7];
    const float* c2a_w   = (const float*)d_in[8];
    const float* c2a_b   = (const float*)d_in[9];
    const float* c2b_w   = (const float*)d_in[10];
    const float* c2b_b   = (const float*)d_in[11];
    const float* ln2_g   = (const float*)d_in[12];
    const float* ln2_b   = (const float*)d_in[13];
    const float* lin_w   = (const float*)d_in[14];
    const float* lin_b   = (const float*)d_in[15];

    const int T = (out_size - B_ * L_) / (B_ * D_);
    float* out_gather = (float*)d_out;
    float* out_dur    = (float*)d_out + (size_t)B_ * T * D_;

    // workspace layout
    char* p = (char*)d_ws;
    __bf16* xb  = (__bf16*)p; p += (size_t)M_ * D_ * 2;
    __bf16* h1  = (__bf16*)p; p += (size_t)M_ * D_ * 2;
    __bf16* h2  = (__bf16*)p; p += (size_t)M_ * D_ * 2;
    __bf16* w1a = (__bf16*)p; p += (size_t)D_ * KTOT * 2;
    __bf16* w1b = (__bf16*)p; p += (size_t)D_ * KTOT * 2;
    __bf16* w2a = (__bf16*)p; p += (size_t)D_ * KTOT * 2;
    __bf16* w2b = (__bf16*)p; p += (size_t)D_ * KTOT * 2;
    int* cum = (int*)p; p += (size_t)B_ * L_ * 4;

    // LR path (independent of predictor chain)
    cum_kernel<<<B_, 64, 0, stream>>>(dur, cum);
    gather_kernel<<<B_ * T, 128, 0, stream>>>(x, cum, out_gather, T);

    // predictor chain
    dim3 rpgrid((D_ * KTOT + 255) / 256, 4);
    repack4_kernel<<<rpgrid, 256, 0, stream>>>(c1a_w, c1b_w, c2a_w, c2b_w, w1a, w1b, w2a, w2b);

    dim3 ggrid(M_ / BM, D_ / BN);  // 256 x 6 = 1536 blocks = 6 per CU
    conv_gemm<true ><<<ggrid, 128, 0, stream>>>(x,  w1a, c1a_b, h1);  // converts x on the fly
    conv_gemm<false><<<ggrid, 128, 0, stream>>>(h1, w1b, c1b_b, h2);
    ln_kernel<<<M_ / 4, 256, 0, stream>>>(h2, ln1_g, ln1_b, xb);
    conv_gemm<false><<<ggrid, 128, 0, stream>>>(xb, w2a, c2a_b, h1);
    conv_gemm<false><<<ggrid, 128, 0, stream>>>(h1, w2b, c2b_b, h2);
    ln_kernel<<<M_ / 4, 256, 0, stream>>>(h2, ln2_g, ln2_b, xb);
    head_kernel<<<M_ / 4, 256, 0, stream>>>(xb, lin_w, lin_b, out_dur);
}

// Round 8
// 253.910 us; speedup vs baseline: 1.6375x; 1.1433x over previous
//
#include <hip/hip_runtime.h>

#define B_   32
#define L_   512
#define D_   384
#define M_   (B_*L_)    // 16384 rows
#define KTOT (D_*3)     // 1152 GEMM K
#define LDW  392        // LDS row stride in bf16 elems (784B: 16B-aligned, 2-way bank alias)
#define BROWS 82        // 80 data rows + 2 guard rows
#define BUFE (BROWS*LDW)

typedef __bf16 bf16x8 __attribute__((ext_vector_type(8)));
typedef float  floatx4 __attribute__((ext_vector_type(4)));

// ---------------- weight repack: chunk-major fragment layout (unchanged from r7) ----
// W3[((c*24 + t)*64 + lane)*8 + j] = w[o = t*16 + (lane&15)][kflat = c*32 + (lane>>4)*8 + j]
// kflat = s*384 + i.
__global__ __launch_bounds__(256) void repack4_kernel(const float* __restrict__ wa,
                                                      const float* __restrict__ wb,
                                                      const float* __restrict__ wc,
                                                      const float* __restrict__ wd,
                                                      __bf16* __restrict__ oa,
                                                      __bf16* __restrict__ ob,
                                                      __bf16* __restrict__ oc,
                                                      __bf16* __restrict__ od)
{
    int idx = blockIdx.x * 256 + threadIdx.x;
    if (idx >= D_ * KTOT) return;
    const float* w; __bf16* o_;
    switch (blockIdx.y) {
        case 0:  w = wa; o_ = oa; break;
        case 1:  w = wb; o_ = ob; break;
        case 2:  w = wc; o_ = oc; break;
        default: w = wd; o_ = od; break;
    }
    int j  = idx & 7;
    int l  = (idx >> 3) & 63;
    int ct = idx >> 9;          // c*24 + t
    int c  = ct / 24;
    int t  = ct - c * 24;
    int o  = t * 16 + (l & 15);
    int kflat = c * 32 + (l >> 4) * 8 + j;
    int s  = kflat / D_;
    int i  = kflat - s * D_;
    o_[idx] = (__bf16)w[(o * D_ + i) * 3 + s];
}

// ---------------- fused DurationPredictor: 4 convs + 2 LN + head, ONE kernel ------
// Block = 512 threads (8 waves) owns 64 output rows (seq rows l0..l0+63).
// LDS: two 82-row x 384-col bf16 buffers (rows beta=1..80 ~ seq l0-8..l0+71,
// rows 0/81 zero guards) + reduction scratch. Halo-shrink: stage k's correct
// rows are [1+k, 80-k]; after 4 convs [5,76] superset of needed [9,72].
// Each stage: K-loop (36 steps; LDS A-frags, c-major W3 B-frags 2-ahead
// prefetched) -> relu+bias epilogue [-> LN via cross-wave LDS reduce]
// -> LDS write (zero for out-of-seq rows = SAME padding). Head fused at end.
__global__ __launch_bounds__(512, 1) void fused_predictor(
    const float* __restrict__ x,
    const __bf16* __restrict__ w1a, const float* __restrict__ b1a,
    const __bf16* __restrict__ w1b, const float* __restrict__ b1b,
    const float* __restrict__ g1,  const float* __restrict__ e1,
    const __bf16* __restrict__ w2a, const float* __restrict__ b2a,
    const __bf16* __restrict__ w2b, const float* __restrict__ b2b,
    const float* __restrict__ g2,  const float* __restrict__ e2,
    const float* __restrict__ lw,  const float* __restrict__ lb,
    float* __restrict__ out_dur)
{
    extern __shared__ char smem_raw[];
    __bf16* bufA = (__bf16*)smem_raw;
    __bf16* bufB = bufA + BUFE;
    float*  red1 = (float*)(bufB + BUFE);    // [BROWS][8]
    float*  red2 = red1 + BROWS * 8;         // [BROWS][8]
    float*  minv = red2 + BROWS * 8;         // [BROWS][2]

    const int m0 = blockIdx.x * 64;
    const int l0 = m0 & 511;
    const int b0 = m0 - l0;

    const int tid  = threadIdx.x;
    const int wave = tid >> 6;        // 0..7; owns cols [wave*48, wave*48+48)
    const int lane = tid & 63;
    const int quad = lane >> 4;
    const int lx   = lane & 15;

    bf16x8 kz;
#pragma unroll
    for (int z = 0; z < 8; z++) kz[z] = (__bf16)0.f;

    // ---- stage x -> bufA (fp32->bf16, zero outside seq); zero bufB guards ----
    for (int c = tid; c < BROWS * 48; c += 512) {
        int beta = c / 48, q = c - beta * 48;
        int l = l0 + beta - 9;
        bf16x8 v = kz;
        if ((unsigned)l < (unsigned)L_) {
            const float* xr = x + (size_t)(b0 + l) * D_ + q * 8;
            const float4 f0 = *(const float4*)xr;
            const float4 f1 = *(const float4*)(xr + 4);
            v[0] = (__bf16)f0.x; v[1] = (__bf16)f0.y; v[2] = (__bf16)f0.z; v[3] = (__bf16)f0.w;
            v[4] = (__bf16)f1.x; v[5] = (__bf16)f1.y; v[6] = (__bf16)f1.z; v[7] = (__bf16)f1.w;
        }
        *(bf16x8*)(&bufA[beta * LDW + q * 8]) = v;
    }
    for (int c = tid; c < 2 * 48; c += 512) {
        int beta = (c < 48) ? 0 : 81, q = c % 48;
        *(bf16x8*)(&bufB[beta * LDW + q * 8]) = kz;
    }
    __syncthreads();

    const int t0  = wave * 3;                 // n-tiles of this wave
    const int col0 = wave * 48 + lx;          // col for ni: col0 + ni*16

    floatx4 acc[5][3];
    bf16x8  bg[3][3];

    for (int st = 0; st < 4; st++) {
        const __bf16* bin  = (st & 1) ? bufB : bufA;
        __bf16*       bout = (st & 1) ? bufA : bufB;
        const __bf16* Wp = (st == 0) ? w1a : (st == 1) ? w1b : (st == 2) ? w2a : w2b;
        const float*  bp = (st == 0) ? b1a : (st == 1) ? b1b : (st == 2) ? b2a : b2b;

#pragma unroll
        for (int mt = 0; mt < 5; mt++)
#pragma unroll
            for (int ni = 0; ni < 3; ni++)
#pragma unroll
                for (int r = 0; r < 4; r++) acc[mt][ni][r] = 0.f;

        const char* pb0 = (const char*)Wp + ((size_t)t0 * 64 + lane) * 16;
        auto loadB = [&](int buf, int n) {
            int it = n / 3, s = n - it * 3;
            const char* p = pb0 + (size_t)(s * 12 + it) * 24576;
#pragma unroll
            for (int ni = 0; ni < 3; ni++)
                bg[buf][ni] = *(const bf16x8*)(p + ni * 1024);
        };
        loadB(0, 0); loadB(1, 1);

        const __bf16* ab = bin + lx * LDW + quad * 8;
#pragma unroll
        for (int n = 0; n < 36; n++) {
            const int it = n / 3, s = n - it * 3;
            if (n + 2 < 36) loadB((n + 2) % 3, n + 2);
            bf16x8 af[5];
#pragma unroll
            for (int mt = 0; mt < 5; mt++)
                af[mt] = *(const bf16x8*)(ab + (mt * 16 + s) * LDW + it * 32);
#pragma unroll
            for (int mt = 0; mt < 5; mt++)
#pragma unroll
                for (int ni = 0; ni < 3; ni++)
                    acc[mt][ni] = __builtin_amdgcn_mfma_f32_16x16x32_bf16(af[mt], bg[n % 3][ni], acc[mt][ni], 0, 0, 0);
        }

        // ---- epilogue: bias + relu (in place) ----
        float bv[3];
#pragma unroll
        for (int ni = 0; ni < 3; ni++) bv[ni] = bp[col0 + ni * 16];
#pragma unroll
        for (int mt = 0; mt < 5; mt++)
#pragma unroll
            for (int ni = 0; ni < 3; ni++)
#pragma unroll
                for (int r = 0; r < 4; r++) {
                    float vv = acc[mt][ni][r] + bv[ni];
                    acc[mt][ni][r] = vv > 0.f ? vv : 0.f;
                }

        if (st == 1 || st == 3) {
            // ---- LayerNorm: row stats via lx-shuffle + cross-wave LDS reduce ----
#pragma unroll
            for (int mt = 0; mt < 5; mt++)
#pragma unroll
                for (int r = 0; r < 4; r++) {
                    float s1 = acc[mt][0][r] + acc[mt][1][r] + acc[mt][2][r];
                    float s2 = acc[mt][0][r] * acc[mt][0][r] + acc[mt][1][r] * acc[mt][1][r]
                             + acc[mt][2][r] * acc[mt][2][r];
#pragma unroll
                    for (int d = 1; d < 16; d <<= 1) {
                        s1 += __shfl_xor(s1, d);
                        s2 += __shfl_xor(s2, d);
                    }
                    if (lx == 0) {
                        int beta = mt * 16 + quad * 4 + r + 1;
                        red1[beta * 8 + wave] = s1;
                        red2[beta * 8 + wave] = s2;
                    }
                }
            __syncthreads();
            if (tid < BROWS) {
                float s1 = 0.f, s2 = 0.f;
#pragma unroll
                for (int w = 0; w < 8; w++) { s1 += red1[tid * 8 + w]; s2 += red2[tid * 8 + w]; }
                float mean = s1 * (1.f / D_);
                float var  = s2 * (1.f / D_) - mean * mean;
                minv[tid * 2]     = mean;
                minv[tid * 2 + 1] = rsqrtf(var + 1e-5f);
            }
            __syncthreads();
            const float* gp = (st == 1) ? g1 : g2;
            const float* ep = (st == 1) ? e1 : e2;
            float gv[3], ev[3];
#pragma unroll
            for (int ni = 0; ni < 3; ni++) { gv[ni] = gp[col0 + ni * 16]; ev[ni] = ep[col0 + ni * 16]; }
#pragma unroll
            for (int mt = 0; mt < 5; mt++)
#pragma unroll
                for (int r = 0; r < 4; r++) {
                    int beta = mt * 16 + quad * 4 + r + 1;
                    float mean = minv[beta * 2], inv = minv[beta * 2 + 1];
#pragma unroll
                    for (int ni = 0; ni < 3; ni++)
                        acc[mt][ni][r] = (acc[mt][ni][r] - mean) * inv * gv[ni] + ev[ni];
                }
            if (st == 1) {
#pragma unroll
                for (int mt = 0; mt < 5; mt++)
#pragma unroll
                    for (int r = 0; r < 4; r++) {
                        int beta = mt * 16 + quad * 4 + r + 1;
                        bool ok = (unsigned)(l0 + beta - 9) < (unsigned)L_;
#pragma unroll
                        for (int ni = 0; ni < 3; ni++)
                            bout[beta * LDW + col0 + ni * 16] = (__bf16)(ok ? acc[mt][ni][r] : 0.f);
                    }
            } else {
                // ---- head: dot with lin_w, cross-wave reduce, store dur_preds ----
                float lwv[3];
#pragma unroll
                for (int ni = 0; ni < 3; ni++) lwv[ni] = lw[col0 + ni * 16];
#pragma unroll
                for (int mt = 0; mt < 5; mt++)
#pragma unroll
                    for (int r = 0; r < 4; r++) {
                        float p = acc[mt][0][r] * lwv[0] + acc[mt][1][r] * lwv[1] + acc[mt][2][r] * lwv[2];
#pragma unroll
                        for (int d = 1; d < 16; d <<= 1) p += __shfl_xor(p, d);
                        if (lx == 0) {
                            int beta = mt * 16 + quad * 4 + r + 1;
                            red1[beta * 8 + wave] = p;
                        }
                    }
                __syncthreads();
                if (tid < 64) {
                    int beta = tid + 9;
                    float sacc = lb[0];
#pragma unroll
                    for (int w = 0; w < 8; w++) sacc += red1[beta * 8 + w];
                    out_dur[m0 + tid] = sacc;
                }
            }
        } else {
            // ---- plain write (conv1a / conv2a outputs) ----
#pragma unroll
            for (int mt = 0; mt < 5; mt++)
#pragma unroll
                for (int r = 0; r < 4; r++) {
                    int beta = mt * 16 + quad * 4 + r + 1;
                    bool ok = (unsigned)(l0 + beta - 9) < (unsigned)L_;
#pragma unroll
                    for (int ni = 0; ni < 3; ni++)
                        bout[beta * LDW + col0 + ni * 16] = (__bf16)(ok ? acc[mt][ni][r] : 0.f);
                }
        }
        __syncthreads();
    }
}

// ---------------- cumsum of durations, wave per batch ----------------
__global__ __launch_bounds__(64) void cum_kernel(const int* __restrict__ dur,
                                                 int* __restrict__ cum)
{
    int b = blockIdx.x, lane = threadIdx.x;
    const int* db = dur + b * L_;
    int v[8], s = 0;
#pragma unroll
    for (int i = 0; i < 8; i++) { v[i] = db[lane * 8 + i]; s += v[i]; }
    int ex = s;
#pragma unroll
    for (int off = 1; off < 64; off <<= 1) {
        int n = __shfl_up(ex, off);
        if (lane >= off) ex += n;
    }
    ex -= s;
    int c = ex;
    int* cb = cum + b * L_;
#pragma unroll
    for (int i = 0; i < 8; i++) { c += v[i]; cb[lane * 8 + i] = c; }
}

// ---------------- gather / length-regulate, block per frame ----------------
__global__ __launch_bounds__(128) void gather_kernel(const float* __restrict__ x,
                                                     const int* __restrict__ cum,
                                                     float* __restrict__ out, int T)
{
    int fr = blockIdx.x;
    int b  = fr / T;
    int t  = fr - b * T;
    int tid = threadIdx.x;
    const int* cb = cum + b * L_;
    int total = cb[L_ - 1];
    float4 val = make_float4(0.f, 0.f, 0.f, 0.f);
    if (t < total) {
        int lo = 0, hi = L_;
        while (lo < hi) { int mid = (lo + hi) >> 1; if (cb[mid] > t) hi = mid; else lo = mid + 1; }
        if (tid < 96) val = *(const float4*)(x + ((size_t)(b * L_ + lo)) * D_ + tid * 4);
    }
    if (tid < 96) *(float4*)(out + (size_t)fr * D_ + tid * 4) = val;
}

extern "C" void kernel_launch(void* const* d_in, const int* in_sizes, int n_in,
                              void* d_out, int out_size, void* d_ws, size_t ws_size,
                              hipStream_t stream) {
    const float* x       = (const float*)d_in[0];
    const int*   dur     = (const int*)d_in[1];
    const float* c1a_w   = (const float*)d_in[2];
    const float* c1a_b   = (const float*)d_in[3];
    const float* c1b_w   = (const float*)d_in[4];
    const float* c1b_b   = (const float*)d_in[5];
    const float* ln1_g   = (const float*)d_in[6];
    const float* ln1_b   = (const float*)d_in[7];
    const float* c2a_w   = (const float*)d_in[8];
    const float* c2a_b   = (const float*)d_in[9];
    const float* c2b_w   = (const float*)d_in[10];
    const float* c2b_b   = (const float*)d_in[11];
    const float* ln2_g   = (const float*)d_in[12];
    const float* ln2_b   = (const float*)d_in[13];
    const float* lin_w   = (const float*)d_in[14];
    const float* lin_b   = (const float*)d_in[15];

    const int T = (out_size - B_ * L_) / (B_ * D_);
    float* out_gather = (float*)d_out;
    float* out_dur    = (float*)d_out + (size_t)B_ * T * D_;

    // workspace: 4 repacked weights + cumsum
    char* p = (char*)d_ws;
    __bf16* w1a = (__bf16*)p; p += (size_t)D_ * KTOT * 2;
    __bf16* w1b = (__bf16*)p; p += (size_t)D_ * KTOT * 2;
    __bf16* w2a = (__bf16*)p; p += (size_t)D_ * KTOT * 2;
    __bf16* w2b = (__bf16*)p; p += (size_t)D_ * KTOT * 2;
    int* cum = (int*)p; p += (size_t)B_ * L_ * 4;

    // LR path (independent of predictor chain)
    cum_kernel<<<B_, 64, 0, stream>>>(dur, cum);
    gather_kernel<<<B_ * T, 128, 0, stream>>>(x, cum, out_gather, T);

    // predictor chain: repack -> one fused kernel
    dim3 rpgrid((D_ * KTOT + 255) / 256, 4);
    repack4_kernel<<<rpgrid, 256, 0, stream>>>(c1a_w, c1b_w, c2a_w, c2b_w, w1a, w1b, w2a, w2b);

    const size_t smem = (size_t)2 * BUFE * 2 + (BROWS * 8 * 2 + BROWS * 2) * 4;  // 134480 B
    static bool attr_set = false;
    if (!attr_set) {
        hipFuncSetAttribute((const void*)fused_predictor,
                            hipFuncAttributeMaxDynamicSharedMemorySize, (int)smem);
        attr_set = true;
    }
    fused_predictor<<<256, 512, smem, stream>>>(
        x, w1a, c1a_b, w1b, c1b_b, ln1_g, ln1_b,
        w2a, c2a_b, w2b, c2b_b, ln2_g, ln2_b,
        lin_w, lin_b, out_dur);
}